// Round 9
// baseline (250.653 us; speedup 1.0000x reference)
//
#include <hip/hip_runtime.h>
#include <cstdint>

#define NN 2048
#define DD 128
#define BATCH 8
#define NROWS 16384
#define MARGIN 0.02f     // need: 2E (fp32-vs-fp64 dot discrepancy) ~= 0.016; 0.02 holds
#define CAP2 64

typedef __attribute__((ext_vector_type(8))) short bf16x8;
typedef __attribute__((ext_vector_type(4))) float f32x4;
typedef unsigned long long u64;
typedef unsigned int u32;
typedef unsigned short u16;

__device__ __forceinline__ u32 bf16rne(float f) {
  u32 u = __float_as_uint(f);
  return (u + 0x7fffu + ((u >> 16) & 1u)) >> 16;
}
// round toward +inf to 16-bit bf16 payload: result value >= f always
__device__ __forceinline__ u32 bf16up(float f) {
  const u32 u = __float_as_uint(f);
  return (u + (((int)u >= 0) ? 0xFFFFu : 0u)) >> 16;
}

// ---------------- K1: norms + bf16 normalized copy (validated R14-R17) + output zero ----------------
__global__ __launch_bounds__(256) void k_normalize(const float* __restrict__ x,
                                                   double* __restrict__ rinv,
                                                   u32* __restrict__ nb,
                                                   float4* __restrict__ outz) {
  const int wave = threadIdx.x >> 6, lane = threadIdx.x & 63;
  const long long row = (long long)blockIdx.x * 4 + wave;   // 16384 rows
  float2 v = ((const float2*)(x + row * DD))[lane];
  const double d0 = v.x, d1 = v.y;
  double s = d0 * d0 + d1 * d1;
  #pragma unroll
  for (int m = 32; m >= 1; m >>= 1) s += __shfl_xor(s, m, 64);
  double den = sqrt(s); den = den > 1e-12 ? den : 1e-12;
  if (lane == 0) rinv[row] = 1.0 / den;
  double2 o; o.x = d0 / den; o.y = d1 / den;
  nb[row * (DD / 2) + lane] = bf16rne((float)o.x) | (bf16rne((float)o.y) << 16);

  // output zero tail: 1,048,576 threads x 8 float4 = 134 MB (validated R25)
  {
    const int base = blockIdx.x * 256 + threadIdx.x;
    const float4 zf = {0.0f, 0.0f, 0.0f, 0.0f};
    #pragma unroll
    for (int k = 0; k < 8; ++k) outz[base + k * 1048576] = zf;
  }
}

// ---------------- fp32 top-8 machinery: branch-free merge (validated R12/R18) ----------------
#define CXF(i, j) { const float a_ = L[i], b_ = L[j]; L[i] = fmaxf(a_, b_); L[j] = fminf(a_, b_); }
__device__ __forceinline__ void merge8f(float (&kv)[8], const float (&ov)[8]) {
  float L[8];
  #pragma unroll
  for (int i = 0; i < 8; ++i) L[i] = fmaxf(kv[i], ov[7 - i]);
  CXF(0, 4) CXF(1, 5) CXF(2, 6) CXF(3, 7)
  CXF(0, 2) CXF(1, 3) CXF(4, 6) CXF(5, 7)
  CXF(0, 1) CXF(2, 3) CXF(4, 5) CXF(6, 7)
  #pragma unroll
  for (int i = 0; i < 8; ++i) kv[i] = L[i];
}

// ---------------- u64 exact-key machinery (validated R5-R17) ----------------
__device__ __forceinline__ u64 make_key(double s, int col) {
  u64 u = (u64)__double_as_longlong(s);
  const u64 m = (u64)((long long)u >> 63);
  u ^= (m | 0x8000000000000000ull);
  return (u & ~2047ull) | (u64)(2047 - col);
}
__device__ __forceinline__ u64 umax64(u64 a, u64 b) { return a > b ? a : b; }
__device__ __forceinline__ u64 umin64(u64 a, u64 b) { return a > b ? b : a; }
__device__ __forceinline__ void merge8(u64 (&kv)[8], const u64 (&ov)[8]) {
  u64 L[8];
  #pragma unroll
  for (int i = 0; i < 8; ++i) L[i] = umax64(kv[i], ov[7 - i]);
#define CX(i, j) { const u64 a_ = L[i], b_ = L[j]; L[i] = umax64(a_, b_); L[j] = umin64(a_, b_); }
  CX(0, 4) CX(1, 5) CX(2, 6) CX(3, 7)
  CX(0, 2) CX(1, 3) CX(4, 6) CX(5, 7)
  CX(0, 1) CX(2, 3) CX(4, 5) CX(6, 7)
#undef CX
  #pragma unroll
  for (int i = 0; i < 8; ++i) kv[i] = L[i];
}
__device__ __forceinline__ void insert8u(u64 (&v)[8], u64 nk) {
  if (nk > v[7]) {
    v[7] = nk;
    #pragma unroll
    for (int q = 7; q >= 1; --q) {
      const u64 a = v[q - 1], b = v[q];
      const bool sw = b > a;
      v[q - 1] = sw ? b : a; v[q] = sw ? a : b;
    }
  }
}

// ---------------- k_build R26: ONE MFMA pass, scores kept in VGPRs ----------------
// Block = 32 rows x 2048 cols, 8 waves x private 256-col strip, 512 blocks (2/CU).
// Pass 1: MFMA all tiles; per-tile f32 accs -> (a) per-16col block max -> LDS f32,
// (b) PACKED bf16 round-up copy in VGPRs (vup >= v32 => filter superset preserved;
// 32 tiles x 2 uint = 64 regs). Phase A: per-row threshold = 8th-largest lane-max of
// block maxes - MARGIN (validated butterfly). Filter: compare packed vup vs th from
// REGISTERS -- no second B sweep. Phase C: validated 16-lane-group fp64 rescore.
__global__ __launch_bounds__(512, 4) void k_build(const u32* __restrict__ nb,
                                                  const float* __restrict__ x,
                                                  const double* __restrict__ rinv,
                                                  float* __restrict__ out) {
  __shared__ float bmf[32][130];   // [row][block 0..127]+pad : 16.6 KB
  __shared__ float thl[32];
  __shared__ u32 cnt[32];
  __shared__ u32 cand[32][CAP2];   // 8 KB

  const int tid = threadIdx.x; const int w = tid >> 6; const int l = tid & 63; // w: 0..7
  const int q = l >> 4; const int m = l & 15;
  const int row0 = blockIdx.x * 32;            // 512 blocks x 32 rows
  const int b = blockIdx.x >> 6;               // batch
  const long long brow = (long long)b * NN;

  // ---- runtime MFMA layout probe (validated R17) ----
  bf16x8 pvals = {0,0,0,0,0,0,0,0}, pones = {0,0,0,0,0,0,0,0};
  if (q == 0) {
    pvals[0] = (short)(__float_as_uint((float)(m + 1)) >> 16);
    pones[0] = (short)(__float_as_uint(1.0f) >> 16);
  }
  const f32x4 z4 = {0.0f, 0.0f, 0.0f, 0.0f};
  const f32x4 pr  = __builtin_amdgcn_mfma_f32_16x16x32_bf16(pvals, pones, z4, 0, 0, 0);
  const f32x4 pr2 = __builtin_amdgcn_mfma_f32_16x16x32_bf16(pones, pvals, z4, 0, 0, 0);
  int cof[4];
  #pragma unroll
  for (int p = 0; p < 4; ++p) cof[p] = (int)pr[p] - 1;
  const int rof = (int)pr2[0] - 1;

  if (tid < 32) cnt[tid] = 0u;

  // A fragments for the block's 32 rows (2 row-frags)
  bf16x8 ar4[2][4];
  #pragma unroll
  for (int rf = 0; rf < 2; ++rf) {
    const u32* Ap = nb + (long long)(row0 + 16 * rf + m) * (DD / 2) + 4 * q;
    #pragma unroll
    for (int cc = 0; cc < 4; ++cc) ar4[rf][cc] = *(const bf16x8*)(Ap + 16 * cc);
  }

  const int c0w = w * 256;                     // this wave's private 256-col strip
  const u32* Bb = nb + (brow + c0w) * (DD / 2);
  bf16x8 bc[4];
  uint2 pk[32];                                // [t*2+rf]: 4 bf16-up scores each

  // ---- Pass 1: MFMA sweep; block-max -> LDS, packed scores -> VGPRs ----
  #pragma unroll
  for (int t = 0; t < 16; ++t) {
    { const u32* p_ = Bb + (long long)(16 * t + m) * (DD / 2) + 4 * q;
      #pragma unroll
      for (int cc = 0; cc < 4; ++cc) bc[cc] = *(const bf16x8*)(p_ + 16 * cc); }
    #pragma unroll
    for (int rf = 0; rf < 2; ++rf) {
      f32x4 acc = z4;
      #pragma unroll
      for (int cc = 0; cc < 4; ++cc)
        acc = __builtin_amdgcn_mfma_f32_16x16x32_bf16(bc[cc], ar4[rf][cc], acc, 0, 0, 0);
      float bm_ = fmaxf(fmaxf(acc[0], acc[1]), fmaxf(acc[2], acc[3]));
      bm_ = fmaxf(bm_, __shfl_xor(bm_, 16, 64));
      bm_ = fmaxf(bm_, __shfl_xor(bm_, 32, 64));
      if (q == 0) bmf[16 * rf + m][w * 16 + t] = bm_;
      pk[t * 2 + rf].x = bf16up(acc[0]) | (bf16up(acc[1]) << 16);
      pk[t * 2 + rf].y = bf16up(acc[2]) | (bf16up(acc[3]) << 16);
    }
  }
  __syncthreads();

  // ---- Phase A: per-row thresholds (validated butterfly), 4 rows per wave ----
  for (int j = 0; j < 4; ++j) {
    const int rib = w * 4 + j;
    const float b0 = bmf[rib][2 * l];
    const float b1 = bmf[rib][2 * l + 1];
    float mx = fmaxf(b0, b1);
    float kv8[8];
    {
      const float o  = __shfl_xor(mx, 1, 64);
      const float h2 = fmaxf(mx, o), l2 = fminf(mx, o);
      const float p0 = __shfl_xor(h2, 2, 64), p1 = __shfl_xor(l2, 2, 64);
      const float m0 = fmaxf(h2, p0);
      const float xx = fminf(h2, p0);
      const float yy = fmaxf(l2, p1);
      const float m3 = fminf(l2, p1);
      const float m1 = fmaxf(xx, yy);
      const float m2 = fminf(xx, yy);
      const float q0 = __shfl_xor(m0, 4, 64), q1 = __shfl_xor(m1, 4, 64);
      const float q2 = __shfl_xor(m2, 4, 64), q3 = __shfl_xor(m3, 4, 64);
      float L[8] = {m0, m1, m2, m3, q3, q2, q1, q0};
      CXF(0, 4) CXF(1, 5) CXF(2, 6) CXF(3, 7)
      CXF(0, 2) CXF(1, 3) CXF(4, 6) CXF(5, 7)
      CXF(0, 1) CXF(2, 3) CXF(4, 5) CXF(6, 7)
      #pragma unroll
      for (int s = 0; s < 8; ++s) kv8[s] = L[s];
      #pragma unroll
      for (int mk = 8; mk <= 32; mk <<= 1) {
        float ov[8];
        #pragma unroll
        for (int s = 0; s < 8; ++s) ov[s] = __shfl_xor(kv8[s], mk, 64);
        merge8f(kv8, ov);
      }
    }
    if (l == 0) thl[rib] = kv8[7] - MARGIN;
  }
  __syncthreads();

  // ---- Filter from REGISTERS: compare packed round-up scores vs thresholds ----
  {
    float th2[2]; int rib2[2];
    #pragma unroll
    for (int rf = 0; rf < 2; ++rf) {
      rib2[rf] = 16 * rf + rof;
      th2[rf] = thl[rib2[rf]];
    }
    #pragma unroll
    for (int t = 0; t < 16; ++t)
      #pragma unroll
      for (int rf = 0; rf < 2; ++rf) {
        const uint2 pv = pk[t * 2 + rf];
        float v0 = __uint_as_float(pv.x << 16);
        float v1 = __uint_as_float(pv.x & 0xFFFF0000u);
        float v2 = __uint_as_float(pv.y << 16);
        float v3 = __uint_as_float(pv.y & 0xFFFF0000u);
        #pragma unroll
        for (int p = 0; p < 4; ++p) {
          const float vv = (p == 0) ? v0 : (p == 1) ? v1 : (p == 2) ? v2 : v3;
          if (vv >= th2[rf]) {
            const u32 id = atomicAdd(&cnt[rib2[rf]], 1u);
            if (id < CAP2) cand[rib2[rf]][id] = (u32)(c0w + 16 * t + cof[p]);
          }
        }
      }
  }
  __syncthreads();

  // ---- Phase C: fp64 rescore (validated R23 16-lane-group), 4 rows per wave ----
  for (int j = 0; j < 4; ++j) {
    const int rib = w * 4 + j;
    const int r = row0 + rib;
    const int n = r & (NN - 1);
    const int c = (int)cnt[rib];
    const double ri = rinv[r];
    u64 kv[8];
    #pragma unroll
    for (int s = 0; s < 8; ++s) kv[s] = 0ull;

    if (c <= CAP2) {
      float2 a4[4];
      #pragma unroll
      for (int jj = 0; jj < 4; ++jj)
        a4[jj] = ((const float2*)(x + (long long)r * DD))[m + 16 * jj];

      for (int i = 0; i < c; i += 4) {
        const int gi = i + q;
        const bool valid = gi < c;
        const int col = valid ? (int)cand[rib][gi] : 0;
        const float2* cp = (const float2*)(x + (brow + col) * DD);
        double d = 0.0;
        #pragma unroll
        for (int jj = 0; jj < 4; ++jj) {
          const float2 bv = cp[m + 16 * jj];
          d = fma((double)a4[jj].x, (double)bv.x, d);
          d = fma((double)a4[jj].y, (double)bv.y, d);
        }
        #pragma unroll
        for (int mk = 1; mk <= 8; mk <<= 1) d += __shfl_xor(d, mk, 64);
        if (valid) insert8u(kv, make_key(d * ri * rinv[brow + col], col));
      }
      #pragma unroll
      for (int mk = 16; mk <= 32; mk <<= 1) {
        u64 ov[8];
        #pragma unroll
        for (int s = 0; s < 8; ++s) ov[s] = __shfl_xor(kv[s], mk, 64);
        merge8(kv, ov);
      }
    } else {
      // overflow fallback (never expected): full exact row scan (validated)
      for (int base = 0; base < NN; base += 64) {
        const int col = base + l;
        const float* ap = x + (long long)r * DD;
        const float* cp2 = x + (brow + col) * DD;
        double d = 0.0;
        for (int kk = 0; kk < 64; ++kk) {
          const float2 av = ((const float2*)ap)[kk];
          const float2 bv = ((const float2*)cp2)[kk];
          d = fma((double)av.x, (double)bv.x, fma((double)av.y, (double)bv.y, d));
        }
        d = d * ri * rinv[brow + col];
        u64 one[8];
        one[0] = make_key(d, col);
        #pragma unroll
        for (int s = 1; s < 8; ++s) one[s] = 0ull;
        #pragma unroll
        for (int mk = 1; mk <= 32; mk <<= 1) {
          u64 ov[8];
          #pragma unroll
          for (int s = 0; s < 8; ++s) ov[s] = __shfl_xor(one[s], mk, 64);
          merge8(one, ov);
        }
        merge8(kv, one);
      }
    }

    const long long orow = (long long)r * NN;
    const long long obase = brow * NN;         // b*NN*NN
    if (l == 8) out[orow + n] = 1.0f;          // self loop
    #pragma unroll
    for (int s = 0; s < 8; ++s) {
      const int mcol = 2047 - (int)(kv[s] & 2047ull);
      if (l == s) {
        out[orow + mcol] = 1.0f;
        out[obase + (long long)mcol * NN + n] = 1.0f;
      }
    }
  }
}

extern "C" void kernel_launch(void* const* d_in, const int* in_sizes, int n_in,
                              void* d_out, int out_size, void* d_ws, size_t ws_size,
                              hipStream_t stream) {
  const float* x = (const float*)d_in[0];
  float* out = (float*)d_out;
  char* ws = (char*)d_ws;
  u32* nb = (u32*)ws;                                //  4,194,304 B (bf16 normed)
  double* rinv = (double*)(ws + 4194304);            //    131,072 B

  hipLaunchKernelGGL(k_normalize, dim3(NROWS / 4), dim3(256), 0, stream, x, rinv, nb,
                     (float4*)out);
  hipLaunchKernelGGL(k_build, dim3(512), dim3(512), 0, stream, nb, x, rinv, out);
}

// Round 10
// 228.326 us; speedup vs baseline: 1.0978x; 1.0978x over previous
//
#include <hip/hip_runtime.h>
#include <cstdint>

#define NN 2048
#define DD 128
#define BATCH 8
#define NROWS 16384
#define MARGIN 0.02f     // need: 2E (fp32-vs-fp64 dot discrepancy) ~= 0.016; 0.02 holds
#define CAP2 64

typedef __attribute__((ext_vector_type(8))) short bf16x8;
typedef __attribute__((ext_vector_type(4))) float f32x4;
typedef unsigned long long u64;
typedef unsigned int u32;
typedef unsigned short u16;

__device__ __forceinline__ u32 bf16rne(float f) {
  u32 u = __float_as_uint(f);
  return (u + 0x7fffu + ((u >> 16) & 1u)) >> 16;
}
// round toward +inf to 16-bit bf16 payload: result value >= f always
__device__ __forceinline__ u32 bf16up(float f) {
  const u32 u = __float_as_uint(f);
  return (u + (((int)u >= 0) ? 0xFFFFu : 0u)) >> 16;
}

// ---------------- K1: norms + bf16 normalized copy (validated R14-R17) + output zero ----------------
__global__ __launch_bounds__(256) void k_normalize(const float* __restrict__ x,
                                                   double* __restrict__ rinv,
                                                   u32* __restrict__ nb,
                                                   float4* __restrict__ outz) {
  const int wave = threadIdx.x >> 6, lane = threadIdx.x & 63;
  const long long row = (long long)blockIdx.x * 4 + wave;   // 16384 rows
  float2 v = ((const float2*)(x + row * DD))[lane];
  const double d0 = v.x, d1 = v.y;
  double s = d0 * d0 + d1 * d1;
  #pragma unroll
  for (int m = 32; m >= 1; m >>= 1) s += __shfl_xor(s, m, 64);
  double den = sqrt(s); den = den > 1e-12 ? den : 1e-12;
  if (lane == 0) rinv[row] = 1.0 / den;
  double2 o; o.x = d0 / den; o.y = d1 / den;
  nb[row * (DD / 2) + lane] = bf16rne((float)o.x) | (bf16rne((float)o.y) << 16);

  // output zero tail: 1,048,576 threads x 8 float4 = 134 MB (validated R25)
  {
    const int base = blockIdx.x * 256 + threadIdx.x;
    const float4 zf = {0.0f, 0.0f, 0.0f, 0.0f};
    #pragma unroll
    for (int k = 0; k < 8; ++k) outz[base + k * 1048576] = zf;
  }
}

// ---------------- fp32 top-8 machinery: branch-free merge (validated R12/R18) ----------------
#define CXF(i, j) { const float a_ = L[i], b_ = L[j]; L[i] = fmaxf(a_, b_); L[j] = fminf(a_, b_); }
__device__ __forceinline__ void merge8f(float (&kv)[8], const float (&ov)[8]) {
  float L[8];
  #pragma unroll
  for (int i = 0; i < 8; ++i) L[i] = fmaxf(kv[i], ov[7 - i]);
  CXF(0, 4) CXF(1, 5) CXF(2, 6) CXF(3, 7)
  CXF(0, 2) CXF(1, 3) CXF(4, 6) CXF(5, 7)
  CXF(0, 1) CXF(2, 3) CXF(4, 5) CXF(6, 7)
  #pragma unroll
  for (int i = 0; i < 8; ++i) kv[i] = L[i];
}

// ---------------- u64 exact-key machinery (validated R5-R17) ----------------
__device__ __forceinline__ u64 make_key(double s, int col) {
  u64 u = (u64)__double_as_longlong(s);
  const u64 m = (u64)((long long)u >> 63);
  u ^= (m | 0x8000000000000000ull);
  return (u & ~2047ull) | (u64)(2047 - col);
}
__device__ __forceinline__ u64 umax64(u64 a, u64 b) { return a > b ? a : b; }
__device__ __forceinline__ u64 umin64(u64 a, u64 b) { return a > b ? b : a; }
__device__ __forceinline__ void merge8(u64 (&kv)[8], const u64 (&ov)[8]) {
  u64 L[8];
  #pragma unroll
  for (int i = 0; i < 8; ++i) L[i] = umax64(kv[i], ov[7 - i]);
#define CX(i, j) { const u64 a_ = L[i], b_ = L[j]; L[i] = umax64(a_, b_); L[j] = umin64(a_, b_); }
  CX(0, 4) CX(1, 5) CX(2, 6) CX(3, 7)
  CX(0, 2) CX(1, 3) CX(4, 6) CX(5, 7)
  CX(0, 1) CX(2, 3) CX(4, 5) CX(6, 7)
#undef CX
  #pragma unroll
  for (int i = 0; i < 8; ++i) kv[i] = L[i];
}
__device__ __forceinline__ void insert8u(u64 (&v)[8], u64 nk) {
  if (nk > v[7]) {
    v[7] = nk;
    #pragma unroll
    for (int q = 7; q >= 1; --q) {
      const u64 a = v[q - 1], b = v[q];
      const bool sw = b > a;
      v[q - 1] = sw ? b : a; v[q] = sw ? a : b;
    }
  }
}

// ---------------- k_build R27: single MFMA pass, scores in VGPRs, SPILL-FREE sizing ----------------
// Block = 32 rows x 2048 cols, 16 waves x private 128-col strip (8 tiles x 2 row-frags).
// pk[16] uint2 = 32 VGPRs (R26's pk[32]=64 spilled against the 128-reg budget ->
// 72 MB scratch traffic, 134 us). Estimated total ~110 regs < 128 at
// __launch_bounds__(1024,4) (4 waves/SIMD). One MFMA sweep: block-max -> LDS f32 +
// packed bf16-round-up scores -> VGPRs (vup >= v32 => superset filter). Phase A:
// validated butterfly thresholds. Filter from registers (no 2nd B sweep). Phase C:
// validated 16-lane-group fp64 rescore.
__global__ __launch_bounds__(1024, 4) void k_build(const u32* __restrict__ nb,
                                                   const float* __restrict__ x,
                                                   const double* __restrict__ rinv,
                                                   float* __restrict__ out) {
  __shared__ float bmf[32][130];   // [row][block 0..127]+pad : 16.6 KB
  __shared__ float thl[32];
  __shared__ u32 cnt[32];
  __shared__ u32 cand[32][CAP2];   // 8 KB

  const int tid = threadIdx.x; const int w = tid >> 6; const int l = tid & 63; // w: 0..15
  const int q = l >> 4; const int m = l & 15;
  const int row0 = blockIdx.x * 32;            // 512 blocks x 32 rows
  const int b = blockIdx.x >> 6;               // batch
  const long long brow = (long long)b * NN;

  // ---- runtime MFMA layout probe (validated R17) ----
  bf16x8 pvals = {0,0,0,0,0,0,0,0}, pones = {0,0,0,0,0,0,0,0};
  if (q == 0) {
    pvals[0] = (short)(__float_as_uint((float)(m + 1)) >> 16);
    pones[0] = (short)(__float_as_uint(1.0f) >> 16);
  }
  const f32x4 z4 = {0.0f, 0.0f, 0.0f, 0.0f};
  const f32x4 pr  = __builtin_amdgcn_mfma_f32_16x16x32_bf16(pvals, pones, z4, 0, 0, 0);
  const f32x4 pr2 = __builtin_amdgcn_mfma_f32_16x16x32_bf16(pones, pvals, z4, 0, 0, 0);
  int cof[4];
  #pragma unroll
  for (int p = 0; p < 4; ++p) cof[p] = (int)pr[p] - 1;
  const int rof = (int)pr2[0] - 1;

  if (tid < 32) cnt[tid] = 0u;

  // A fragments for the block's 32 rows (2 row-frags)
  bf16x8 ar4[2][4];
  #pragma unroll
  for (int rf = 0; rf < 2; ++rf) {
    const u32* Ap = nb + (long long)(row0 + 16 * rf + m) * (DD / 2) + 4 * q;
    #pragma unroll
    for (int cc = 0; cc < 4; ++cc) ar4[rf][cc] = *(const bf16x8*)(Ap + 16 * cc);
  }

  const int c0w = w * 128;                     // this wave's private 128-col strip
  const u32* Bb = nb + (brow + c0w) * (DD / 2);
  bf16x8 bc[4];
  uint2 pk[16];                                // [t*2+rf]: 4 bf16-up scores each (32 VGPR)

  // ---- Pass 1: MFMA sweep; block-max -> LDS, packed round-up scores -> VGPRs ----
  #pragma unroll
  for (int t = 0; t < 8; ++t) {
    { const u32* p_ = Bb + (long long)(16 * t + m) * (DD / 2) + 4 * q;
      #pragma unroll
      for (int cc = 0; cc < 4; ++cc) bc[cc] = *(const bf16x8*)(p_ + 16 * cc); }
    #pragma unroll
    for (int rf = 0; rf < 2; ++rf) {
      f32x4 acc = z4;
      #pragma unroll
      for (int cc = 0; cc < 4; ++cc)
        acc = __builtin_amdgcn_mfma_f32_16x16x32_bf16(bc[cc], ar4[rf][cc], acc, 0, 0, 0);
      float bm_ = fmaxf(fmaxf(acc[0], acc[1]), fmaxf(acc[2], acc[3]));
      bm_ = fmaxf(bm_, __shfl_xor(bm_, 16, 64));
      bm_ = fmaxf(bm_, __shfl_xor(bm_, 32, 64));
      if (q == 0) bmf[16 * rf + m][w * 8 + t] = bm_;
      pk[t * 2 + rf].x = bf16up(acc[0]) | (bf16up(acc[1]) << 16);
      pk[t * 2 + rf].y = bf16up(acc[2]) | (bf16up(acc[3]) << 16);
    }
  }
  __syncthreads();

  // ---- Phase A: per-row thresholds (validated butterfly), 2 rows per wave ----
  for (int j = 0; j < 2; ++j) {
    const int rib = w * 2 + j;
    const float b0 = bmf[rib][2 * l];
    const float b1 = bmf[rib][2 * l + 1];
    float mx = fmaxf(b0, b1);
    float kv8[8];
    {
      const float o  = __shfl_xor(mx, 1, 64);
      const float h2 = fmaxf(mx, o), l2 = fminf(mx, o);
      const float p0 = __shfl_xor(h2, 2, 64), p1 = __shfl_xor(l2, 2, 64);
      const float m0 = fmaxf(h2, p0);
      const float xx = fminf(h2, p0);
      const float yy = fmaxf(l2, p1);
      const float m3 = fminf(l2, p1);
      const float m1 = fmaxf(xx, yy);
      const float m2 = fminf(xx, yy);
      const float q0 = __shfl_xor(m0, 4, 64), q1 = __shfl_xor(m1, 4, 64);
      const float q2 = __shfl_xor(m2, 4, 64), q3 = __shfl_xor(m3, 4, 64);
      float L[8] = {m0, m1, m2, m3, q3, q2, q1, q0};
      CXF(0, 4) CXF(1, 5) CXF(2, 6) CXF(3, 7)
      CXF(0, 2) CXF(1, 3) CXF(4, 6) CXF(5, 7)
      CXF(0, 1) CXF(2, 3) CXF(4, 5) CXF(6, 7)
      #pragma unroll
      for (int s = 0; s < 8; ++s) kv8[s] = L[s];
      #pragma unroll
      for (int mk = 8; mk <= 32; mk <<= 1) {
        float ov[8];
        #pragma unroll
        for (int s = 0; s < 8; ++s) ov[s] = __shfl_xor(kv8[s], mk, 64);
        merge8f(kv8, ov);
      }
    }
    if (l == 0) thl[rib] = kv8[7] - MARGIN;
  }
  __syncthreads();

  // ---- Filter from REGISTERS: packed round-up scores vs thresholds ----
  {
    float th2[2]; int rib2[2];
    #pragma unroll
    for (int rf = 0; rf < 2; ++rf) {
      rib2[rf] = 16 * rf + rof;
      th2[rf] = thl[rib2[rf]];
    }
    #pragma unroll
    for (int t = 0; t < 8; ++t)
      #pragma unroll
      for (int rf = 0; rf < 2; ++rf) {
        const uint2 pv = pk[t * 2 + rf];
        const float v0 = __uint_as_float(pv.x << 16);
        const float v1 = __uint_as_float(pv.x & 0xFFFF0000u);
        const float v2 = __uint_as_float(pv.y << 16);
        const float v3 = __uint_as_float(pv.y & 0xFFFF0000u);
        #pragma unroll
        for (int p = 0; p < 4; ++p) {
          const float vv = (p == 0) ? v0 : (p == 1) ? v1 : (p == 2) ? v2 : v3;
          if (vv >= th2[rf]) {
            const u32 id = atomicAdd(&cnt[rib2[rf]], 1u);
            if (id < CAP2) cand[rib2[rf]][id] = (u32)(c0w + 16 * t + cof[p]);
          }
        }
      }
  }
  __syncthreads();

  // ---- Phase C: fp64 rescore (validated R23 16-lane-group), 2 rows per wave ----
  for (int j = 0; j < 2; ++j) {
    const int rib = w * 2 + j;
    const int r = row0 + rib;
    const int n = r & (NN - 1);
    const int c = (int)cnt[rib];
    const double ri = rinv[r];
    u64 kv[8];
    #pragma unroll
    for (int s = 0; s < 8; ++s) kv[s] = 0ull;

    if (c <= CAP2) {
      float2 a4[4];
      #pragma unroll
      for (int jj = 0; jj < 4; ++jj)
        a4[jj] = ((const float2*)(x + (long long)r * DD))[m + 16 * jj];

      for (int i = 0; i < c; i += 4) {
        const int gi = i + q;
        const bool valid = gi < c;
        const int col = valid ? (int)cand[rib][gi] : 0;
        const float2* cp = (const float2*)(x + (brow + col) * DD);
        double d = 0.0;
        #pragma unroll
        for (int jj = 0; jj < 4; ++jj) {
          const float2 bv = cp[m + 16 * jj];
          d = fma((double)a4[jj].x, (double)bv.x, d);
          d = fma((double)a4[jj].y, (double)bv.y, d);
        }
        #pragma unroll
        for (int mk = 1; mk <= 8; mk <<= 1) d += __shfl_xor(d, mk, 64);
        if (valid) insert8u(kv, make_key(d * ri * rinv[brow + col], col));
      }
      #pragma unroll
      for (int mk = 16; mk <= 32; mk <<= 1) {
        u64 ov[8];
        #pragma unroll
        for (int s = 0; s < 8; ++s) ov[s] = __shfl_xor(kv[s], mk, 64);
        merge8(kv, ov);
      }
    } else {
      // overflow fallback (never expected): full exact row scan (validated)
      for (int base = 0; base < NN; base += 64) {
        const int col = base + l;
        const float* ap = x + (long long)r * DD;
        const float* cp2 = x + (brow + col) * DD;
        double d = 0.0;
        for (int kk = 0; kk < 64; ++kk) {
          const float2 av = ((const float2*)ap)[kk];
          const float2 bv = ((const float2*)cp2)[kk];
          d = fma((double)av.x, (double)bv.x, fma((double)av.y, (double)bv.y, d));
        }
        d = d * ri * rinv[brow + col];
        u64 one[8];
        one[0] = make_key(d, col);
        #pragma unroll
        for (int s = 1; s < 8; ++s) one[s] = 0ull;
        #pragma unroll
        for (int mk = 1; mk <= 32; mk <<= 1) {
          u64 ov[8];
          #pragma unroll
          for (int s = 0; s < 8; ++s) ov[s] = __shfl_xor(one[s], mk, 64);
          merge8(one, ov);
        }
        merge8(kv, one);
      }
    }

    const long long orow = (long long)r * NN;
    const long long obase = brow * NN;         // b*NN*NN
    if (l == 8) out[orow + n] = 1.0f;          // self loop
    #pragma unroll
    for (int s = 0; s < 8; ++s) {
      const int mcol = 2047 - (int)(kv[s] & 2047ull);
      if (l == s) {
        out[orow + mcol] = 1.0f;
        out[obase + (long long)mcol * NN + n] = 1.0f;
      }
    }
  }
}

extern "C" void kernel_launch(void* const* d_in, const int* in_sizes, int n_in,
                              void* d_out, int out_size, void* d_ws, size_t ws_size,
                              hipStream_t stream) {
  const float* x = (const float*)d_in[0];
  float* out = (float*)d_out;
  char* ws = (char*)d_ws;
  u32* nb = (u32*)ws;                                //  4,194,304 B (bf16 normed)
  double* rinv = (double*)(ws + 4194304);            //    131,072 B

  hipLaunchKernelGGL(k_normalize, dim3(NROWS / 4), dim3(256), 0, stream, x, rinv, nb,
                     (float4*)out);
  hipLaunchKernelGGL(k_build, dim3(512), dim3(1024), 0, stream, nb, x, rinv, out);
}

// Round 11
// 225.391 us; speedup vs baseline: 1.1121x; 1.0130x over previous
//
#include <hip/hip_runtime.h>
#include <cstdint>

#define NN 2048
#define DD 128
#define BATCH 8
#define NROWS 16384
#define MARGIN 0.02f     // need: 2E (fp32-vs-fp64 dot discrepancy) ~= 0.016; 0.02 holds
#define CAP2 64

typedef __attribute__((ext_vector_type(8))) short bf16x8;
typedef __attribute__((ext_vector_type(4))) float f32x4;
typedef unsigned long long u64;
typedef unsigned int u32;
typedef unsigned short u16;

__device__ __forceinline__ u32 bf16rne(float f) {
  u32 u = __float_as_uint(f);
  return (u + 0x7fffu + ((u >> 16) & 1u)) >> 16;
}
// round toward +inf to 16-bit bf16 payload: result value >= f always
__device__ __forceinline__ u32 bf16up(float f) {
  const u32 u = __float_as_uint(f);
  return (u + (((int)u >= 0) ? 0xFFFFu : 0u)) >> 16;
}

// ---------------- K1: norms + bf16 normalized copy (validated R14-R17) + output zero ----------------
__global__ __launch_bounds__(256) void k_normalize(const float* __restrict__ x,
                                                   double* __restrict__ rinv,
                                                   u32* __restrict__ nb,
                                                   float4* __restrict__ outz) {
  const int wave = threadIdx.x >> 6, lane = threadIdx.x & 63;
  const long long row = (long long)blockIdx.x * 4 + wave;   // 16384 rows
  float2 v = ((const float2*)(x + row * DD))[lane];
  const double d0 = v.x, d1 = v.y;
  double s = d0 * d0 + d1 * d1;
  #pragma unroll
  for (int m = 32; m >= 1; m >>= 1) s += __shfl_xor(s, m, 64);
  double den = sqrt(s); den = den > 1e-12 ? den : 1e-12;
  if (lane == 0) rinv[row] = 1.0 / den;
  double2 o; o.x = d0 / den; o.y = d1 / den;
  nb[row * (DD / 2) + lane] = bf16rne((float)o.x) | (bf16rne((float)o.y) << 16);

  // output zero tail: 1,048,576 threads x 8 float4 = 134 MB (validated R25)
  {
    const int base = blockIdx.x * 256 + threadIdx.x;
    const float4 zf = {0.0f, 0.0f, 0.0f, 0.0f};
    #pragma unroll
    for (int k = 0; k < 8; ++k) outz[base + k * 1048576] = zf;
  }
}

// ---------------- fp32 top-8 machinery: branch-free merge (validated R12/R18) ----------------
#define CXF(i, j) { const float a_ = L[i], b_ = L[j]; L[i] = fmaxf(a_, b_); L[j] = fminf(a_, b_); }
__device__ __forceinline__ void merge8f(float (&kv)[8], const float (&ov)[8]) {
  float L[8];
  #pragma unroll
  for (int i = 0; i < 8; ++i) L[i] = fmaxf(kv[i], ov[7 - i]);
  CXF(0, 4) CXF(1, 5) CXF(2, 6) CXF(3, 7)
  CXF(0, 2) CXF(1, 3) CXF(4, 6) CXF(5, 7)
  CXF(0, 1) CXF(2, 3) CXF(4, 5) CXF(6, 7)
  #pragma unroll
  for (int i = 0; i < 8; ++i) kv[i] = L[i];
}

// ---------------- u64 exact-key machinery (validated R5-R17) ----------------
__device__ __forceinline__ u64 make_key(double s, int col) {
  u64 u = (u64)__double_as_longlong(s);
  const u64 m = (u64)((long long)u >> 63);
  u ^= (m | 0x8000000000000000ull);
  return (u & ~2047ull) | (u64)(2047 - col);
}
__device__ __forceinline__ u64 umax64(u64 a, u64 b) { return a > b ? a : b; }
__device__ __forceinline__ u64 umin64(u64 a, u64 b) { return a > b ? b : a; }
__device__ __forceinline__ void merge8(u64 (&kv)[8], const u64 (&ov)[8]) {
  u64 L[8];
  #pragma unroll
  for (int i = 0; i < 8; ++i) L[i] = umax64(kv[i], ov[7 - i]);
#define CX(i, j) { const u64 a_ = L[i], b_ = L[j]; L[i] = umax64(a_, b_); L[j] = umin64(a_, b_); }
  CX(0, 4) CX(1, 5) CX(2, 6) CX(3, 7)
  CX(0, 2) CX(1, 3) CX(4, 6) CX(5, 7)
  CX(0, 1) CX(2, 3) CX(4, 5) CX(6, 7)
#undef CX
  #pragma unroll
  for (int i = 0; i < 8; ++i) kv[i] = L[i];
}
__device__ __forceinline__ void insert8u(u64 (&v)[8], u64 nk) {
  if (nk > v[7]) {
    v[7] = nk;
    #pragma unroll
    for (int q = 7; q >= 1; --q) {
      const u64 a = v[q - 1], b = v[q];
      const bool sw = b > a;
      v[q - 1] = sw ? b : a; v[q] = sw ? a : b;
    }
  }
}

// ---------------- k_build R28: R27 single-pass + XCD-aware batch swizzle ----------------
// R27 (validated spill-free): 32-row block, 16 waves x 128-col strip, pk[16] packed
// round-up scores in VGPRs, one MFMA sweep, validated butterfly/filter/rescore.
// R28: blockIdx swizzle b = bid & 7 -- under round-robin workgroup->XCD dispatch all
// 64 blocks of batch b land on XCD b, so the batch's x-slab (1 MB) + nb-slab (512 KB)
// become L2-resident per XCD (4 MB L2). The harness's 536 MB workspace poison flushes
// caches each iteration; without the swizzle every XCD re-fetches all 8 batches'
// slabs scattered from HBM at ~600 GB/s effective = the observed ~92 us floor.
// Correctness is mapping-independent (speed-only heuristic, G16).
__global__ __launch_bounds__(1024, 4) void k_build(const u32* __restrict__ nb,
                                                   const float* __restrict__ x,
                                                   const double* __restrict__ rinv,
                                                   float* __restrict__ out) {
  __shared__ float bmf[32][130];   // [row][block 0..127]+pad : 16.6 KB
  __shared__ float thl[32];
  __shared__ u32 cnt[32];
  __shared__ u32 cand[32][CAP2];   // 8 KB

  const int tid = threadIdx.x; const int w = tid >> 6; const int l = tid & 63; // w: 0..15
  const int q = l >> 4; const int m = l & 15;
  const int b = blockIdx.x & 7;                // XCD-aligned batch (round-robin dispatch)
  const int rowblk = blockIdx.x >> 3;          // 0..63 within batch
  const int row0 = b * NN + rowblk * 32;       // global row base
  const long long brow = (long long)b * NN;

  // ---- runtime MFMA layout probe (validated R17) ----
  bf16x8 pvals = {0,0,0,0,0,0,0,0}, pones = {0,0,0,0,0,0,0,0};
  if (q == 0) {
    pvals[0] = (short)(__float_as_uint((float)(m + 1)) >> 16);
    pones[0] = (short)(__float_as_uint(1.0f) >> 16);
  }
  const f32x4 z4 = {0.0f, 0.0f, 0.0f, 0.0f};
  const f32x4 pr  = __builtin_amdgcn_mfma_f32_16x16x32_bf16(pvals, pones, z4, 0, 0, 0);
  const f32x4 pr2 = __builtin_amdgcn_mfma_f32_16x16x32_bf16(pones, pvals, z4, 0, 0, 0);
  int cof[4];
  #pragma unroll
  for (int p = 0; p < 4; ++p) cof[p] = (int)pr[p] - 1;
  const int rof = (int)pr2[0] - 1;

  if (tid < 32) cnt[tid] = 0u;

  // A fragments for the block's 32 rows (2 row-frags)
  bf16x8 ar4[2][4];
  #pragma unroll
  for (int rf = 0; rf < 2; ++rf) {
    const u32* Ap = nb + (long long)(row0 + 16 * rf + m) * (DD / 2) + 4 * q;
    #pragma unroll
    for (int cc = 0; cc < 4; ++cc) ar4[rf][cc] = *(const bf16x8*)(Ap + 16 * cc);
  }

  const int c0w = w * 128;                     // this wave's private 128-col strip
  const u32* Bb = nb + (brow + c0w) * (DD / 2);
  bf16x8 bc[4];
  uint2 pk[16];                                // [t*2+rf]: 4 bf16-up scores each (32 VGPR)

  // ---- Pass 1: MFMA sweep; block-max -> LDS, packed round-up scores -> VGPRs ----
  #pragma unroll
  for (int t = 0; t < 8; ++t) {
    { const u32* p_ = Bb + (long long)(16 * t + m) * (DD / 2) + 4 * q;
      #pragma unroll
      for (int cc = 0; cc < 4; ++cc) bc[cc] = *(const bf16x8*)(p_ + 16 * cc); }
    #pragma unroll
    for (int rf = 0; rf < 2; ++rf) {
      f32x4 acc = z4;
      #pragma unroll
      for (int cc = 0; cc < 4; ++cc)
        acc = __builtin_amdgcn_mfma_f32_16x16x32_bf16(bc[cc], ar4[rf][cc], acc, 0, 0, 0);
      float bm_ = fmaxf(fmaxf(acc[0], acc[1]), fmaxf(acc[2], acc[3]));
      bm_ = fmaxf(bm_, __shfl_xor(bm_, 16, 64));
      bm_ = fmaxf(bm_, __shfl_xor(bm_, 32, 64));
      if (q == 0) bmf[16 * rf + m][w * 8 + t] = bm_;
      pk[t * 2 + rf].x = bf16up(acc[0]) | (bf16up(acc[1]) << 16);
      pk[t * 2 + rf].y = bf16up(acc[2]) | (bf16up(acc[3]) << 16);
    }
  }
  __syncthreads();

  // ---- Phase A: per-row thresholds (validated butterfly), 2 rows per wave ----
  for (int j = 0; j < 2; ++j) {
    const int rib = w * 2 + j;
    const float b0 = bmf[rib][2 * l];
    const float b1 = bmf[rib][2 * l + 1];
    float mx = fmaxf(b0, b1);
    float kv8[8];
    {
      const float o  = __shfl_xor(mx, 1, 64);
      const float h2 = fmaxf(mx, o), l2 = fminf(mx, o);
      const float p0 = __shfl_xor(h2, 2, 64), p1 = __shfl_xor(l2, 2, 64);
      const float m0 = fmaxf(h2, p0);
      const float xx = fminf(h2, p0);
      const float yy = fmaxf(l2, p1);
      const float m3 = fminf(l2, p1);
      const float m1 = fmaxf(xx, yy);
      const float m2 = fminf(xx, yy);
      const float q0 = __shfl_xor(m0, 4, 64), q1 = __shfl_xor(m1, 4, 64);
      const float q2 = __shfl_xor(m2, 4, 64), q3 = __shfl_xor(m3, 4, 64);
      float L[8] = {m0, m1, m2, m3, q3, q2, q1, q0};
      CXF(0, 4) CXF(1, 5) CXF(2, 6) CXF(3, 7)
      CXF(0, 2) CXF(1, 3) CXF(4, 6) CXF(5, 7)
      CXF(0, 1) CXF(2, 3) CXF(4, 5) CXF(6, 7)
      #pragma unroll
      for (int s = 0; s < 8; ++s) kv8[s] = L[s];
      #pragma unroll
      for (int mk = 8; mk <= 32; mk <<= 1) {
        float ov[8];
        #pragma unroll
        for (int s = 0; s < 8; ++s) ov[s] = __shfl_xor(kv8[s], mk, 64);
        merge8f(kv8, ov);
      }
    }
    if (l == 0) thl[rib] = kv8[7] - MARGIN;
  }
  __syncthreads();

  // ---- Filter from REGISTERS: packed round-up scores vs thresholds ----
  {
    float th2[2]; int rib2[2];
    #pragma unroll
    for (int rf = 0; rf < 2; ++rf) {
      rib2[rf] = 16 * rf + rof;
      th2[rf] = thl[rib2[rf]];
    }
    #pragma unroll
    for (int t = 0; t < 8; ++t)
      #pragma unroll
      for (int rf = 0; rf < 2; ++rf) {
        const uint2 pv = pk[t * 2 + rf];
        const float v0 = __uint_as_float(pv.x << 16);
        const float v1 = __uint_as_float(pv.x & 0xFFFF0000u);
        const float v2 = __uint_as_float(pv.y << 16);
        const float v3 = __uint_as_float(pv.y & 0xFFFF0000u);
        #pragma unroll
        for (int p = 0; p < 4; ++p) {
          const float vv = (p == 0) ? v0 : (p == 1) ? v1 : (p == 2) ? v2 : v3;
          if (vv >= th2[rf]) {
            const u32 id = atomicAdd(&cnt[rib2[rf]], 1u);
            if (id < CAP2) cand[rib2[rf]][id] = (u32)(c0w + 16 * t + cof[p]);
          }
        }
      }
  }
  __syncthreads();

  // ---- Phase C: fp64 rescore (validated R23 16-lane-group), 2 rows per wave ----
  for (int j = 0; j < 2; ++j) {
    const int rib = w * 2 + j;
    const int r = row0 + rib;
    const int n = r & (NN - 1);
    const int c = (int)cnt[rib];
    const double ri = rinv[r];
    u64 kv[8];
    #pragma unroll
    for (int s = 0; s < 8; ++s) kv[s] = 0ull;

    if (c <= CAP2) {
      float2 a4[4];
      #pragma unroll
      for (int jj = 0; jj < 4; ++jj)
        a4[jj] = ((const float2*)(x + (long long)r * DD))[m + 16 * jj];

      for (int i = 0; i < c; i += 4) {
        const int gi = i + q;
        const bool valid = gi < c;
        const int col = valid ? (int)cand[rib][gi] : 0;
        const float2* cp = (const float2*)(x + (brow + col) * DD);
        double d = 0.0;
        #pragma unroll
        for (int jj = 0; jj < 4; ++jj) {
          const float2 bv = cp[m + 16 * jj];
          d = fma((double)a4[jj].x, (double)bv.x, d);
          d = fma((double)a4[jj].y, (double)bv.y, d);
        }
        #pragma unroll
        for (int mk = 1; mk <= 8; mk <<= 1) d += __shfl_xor(d, mk, 64);
        if (valid) insert8u(kv, make_key(d * ri * rinv[brow + col], col));
      }
      #pragma unroll
      for (int mk = 16; mk <= 32; mk <<= 1) {
        u64 ov[8];
        #pragma unroll
        for (int s = 0; s < 8; ++s) ov[s] = __shfl_xor(kv[s], mk, 64);
        merge8(kv, ov);
      }
    } else {
      // overflow fallback (never expected): full exact row scan (validated)
      for (int base = 0; base < NN; base += 64) {
        const int col = base + l;
        const float* ap = x + (long long)r * DD;
        const float* cp2 = x + (brow + col) * DD;
        double d = 0.0;
        for (int kk = 0; kk < 64; ++kk) {
          const float2 av = ((const float2*)ap)[kk];
          const float2 bv = ((const float2*)cp2)[kk];
          d = fma((double)av.x, (double)bv.x, fma((double)av.y, (double)bv.y, d));
        }
        d = d * ri * rinv[brow + col];
        u64 one[8];
        one[0] = make_key(d, col);
        #pragma unroll
        for (int s = 1; s < 8; ++s) one[s] = 0ull;
        #pragma unroll
        for (int mk = 1; mk <= 32; mk <<= 1) {
          u64 ov[8];
          #pragma unroll
          for (int s = 0; s < 8; ++s) ov[s] = __shfl_xor(one[s], mk, 64);
          merge8(one, ov);
        }
        merge8(kv, one);
      }
    }

    const long long orow = (long long)r * NN;
    const long long obase = brow * NN;         // b*NN*NN
    if (l == 8) out[orow + n] = 1.0f;          // self loop
    #pragma unroll
    for (int s = 0; s < 8; ++s) {
      const int mcol = 2047 - (int)(kv[s] & 2047ull);
      if (l == s) {
        out[orow + mcol] = 1.0f;
        out[obase + (long long)mcol * NN + n] = 1.0f;
      }
    }
  }
}

extern "C" void kernel_launch(void* const* d_in, const int* in_sizes, int n_in,
                              void* d_out, int out_size, void* d_ws, size_t ws_size,
                              hipStream_t stream) {
  const float* x = (const float*)d_in[0];
  float* out = (float*)d_out;
  char* ws = (char*)d_ws;
  u32* nb = (u32*)ws;                                //  4,194,304 B (bf16 normed)
  double* rinv = (double*)(ws + 4194304);            //    131,072 B

  hipLaunchKernelGGL(k_normalize, dim3(NROWS / 4), dim3(256), 0, stream, x, rinv, nb,
                     (float4*)out);
  hipLaunchKernelGGL(k_build, dim3(512), dim3(1024), 0, stream, nb, x, rinv, out);
}